// Round 8
// baseline (333.142 us; speedup 1.0000x reference)
//
#include <hip/hip_runtime.h>
#include <math.h>

#define M0 131072
#define NC 4096
#define FDIM 324   // 6*54

// ---- fine-grained LDS asm loads: value lands in VGPRs, consumed immediately ----
#define DS128(dst, addr, OFF)                                                  \
  asm volatile("ds_read_b128 %0, %1 offset:" #OFF "\n\t"                       \
               "s_waitcnt lgkmcnt(0)"                                          \
               : "=v"(dst) : "v"(addr))

#define DS2X64(dst, addr, O0, O1)                                              \
  asm volatile("ds_read2_b64 %0, %1 offset0:" #O0 " offset1:" #O1 "\n\t"       \
               "s_waitcnt lgkmcnt(0)"                                          \
               : "=v"(dst) : "v"(addr))

#define DS32(dst, addr, OFF)                                                   \
  asm volatile("ds_read_b32 %0, %1 offset:" #OFF "\n\t"                        \
               "s_waitcnt lgkmcnt(0)"                                          \
               : "=v"(dst) : "v"(addr))

// Consume one 4-float chunk (window-relative floats 4M..4M+3) into
// acc[NOUT][NPOS] (NPOS adjacent conv positions), weights stride wstride.
// All indices compile-time after unroll; the k-range test folds away.
template<int M, int NOUT, int NPOS>
__device__ __forceinline__ void consume(const float4 f, float (&acc)[NOUT][NPOS],
                                        const float* __restrict__ w, const int wstride) {
    const float fi[4] = {f.x, f.y, f.z, f.w};
    #pragma unroll
    for (int i = 0; i < 4; ++i) {
        #pragma unroll
        for (int j = 0; j < NPOS; ++j) {
            const int k = 4 * M + i - j;      // weight index for position j
            if (k >= 0 && k < 20) {
                #pragma unroll
                for (int c = 0; c < NOUT; ++c)
                    acc[c][j] = fmaf(fi[i], w[c * wstride + k], acc[c][j]);
            }
        }
    }
}

// -------- Kernel 1: per-atom conv pipeline + atomic segment sum ----------
// One wave per atom; 4 atoms per 256-thread block.
__global__ __launch_bounds__(256, 6) void atom_kernel(
    const float* __restrict__ oh_g,    // [M0,92]
    const float* __restrict__ env_g,   // [M0,55]
    const int*   __restrict__ idx_g,   // [M0] sorted
    const float* __restrict__ wA, const float* __restrict__ bA,  // [3*20],[3]
    const float* __restrict__ w1, const float* __restrict__ b1,  // [3*20],[3]
    const float* __restrict__ w2, const float* __restrict__ b2,  // [6*3*20],[6]
    float* __restrict__ sums,          // [NC,324]
    float* __restrict__ counts)        // [NC]
{
    __shared__ __align__(16) float s_total[4][280];   // concat(atom[219], env[55]) = 274
    __shared__ __align__(16) float s_one1[4][384];    // conv1 pooled [3][128]; first 92 = one-hot scratch

    // XCD-chunk swizzle: contiguous atom ranges per XCD.
    const int bid = (blockIdx.x & 7) * (M0 / 4 / 8) + (blockIdx.x >> 3);

    const int wave = threadIdx.x >> 6;
    const int lane = threadIdx.x & 63;
    const int atom = bid * 4 + wave;

    float* total = s_total[wave];
    float* one1  = s_one1[wave];
    float* oh    = one1;                   // scratch alias: one-hot row [92]

    const int cry = idx_g[atom];

    // ---- Phase A: load one-hot (92) and env (55) ----
    if (lane < 46) {
        const float2 v = *reinterpret_cast<const float2*>(oh_g + (size_t)atom * 92 + 2 * lane);
        oh[2 * lane]     = v.x;
        oh[2 * lane + 1] = v.y;
    }
    if (lane < 55) {
        total[219 + lane] = env_g[(size_t)atom * 55 + lane];
    }
    __syncthreads();

    const unsigned tot_b = (unsigned)(size_t)total;
    const unsigned oh_b  = (unsigned)(size_t)oh;
    const unsigned one_b = (unsigned)(size_t)one1;

    // ---- Phase B: conva -> relu -> total[0..218] ----
    // 37 lanes x 2 positions {2p, 2p+1}; window floats 2p..2p+20 (8B aligned).
    if (lane < 37) {
        const int p2 = 2 * lane;
        float acc[3][2];
        #pragma unroll
        for (int c = 0; c < 3; ++c) { acc[c][0] = bA[c]; acc[c][1] = bA[c]; }
        const unsigned a = oh_b + (unsigned)lane * 8u;
        float4 f;
        DS2X64(f, a, 0, 1);   consume<0, 3, 2>(f, acc, wA, 20);
        DS2X64(f, a, 2, 3);   consume<1, 3, 2>(f, acc, wA, 20);
        DS2X64(f, a, 4, 5);   consume<2, 3, 2>(f, acc, wA, 20);
        DS2X64(f, a, 6, 7);   consume<3, 3, 2>(f, acc, wA, 20);
        DS2X64(f, a, 8, 9);   consume<4, 3, 2>(f, acc, wA, 20);
        float f20;
        DS32(f20, a, 80);     // window float 20: only k=19 for position 2p+1
        #pragma unroll
        for (int c = 0; c < 3; ++c) acc[c][1] = fmaf(f20, wA[c * 20 + 19], acc[c][1]);

        total[      p2] = fmaxf(acc[0][0], 0.f);
        total[ 73 + p2] = fmaxf(acc[1][0], 0.f);
        total[146 + p2] = fmaxf(acc[2][0], 0.f);
        if (p2 + 1 < 73) {
            total[      p2 + 1] = fmaxf(acc[0][1], 0.f);
            total[ 73 + p2 + 1] = fmaxf(acc[1][1], 0.f);
            total[146 + p2 + 1] = fmaxf(acc[2][1], 0.f);
        }
    }
    __syncthreads();

    // ---- Phase C: conv1 (1->3,K=20) + relu + maxpool2 -> one1[3][128] ----
    // ALL 64 lanes: lane q -> pooled {2q, 2q+1} (unpooled 4q..4q+3).
    // Window floats 4q..4q+23 = 6 x ds_read_b128, 16B aligned.
    // q=63: pooled 127 is garbage, stored to dead slot one1[c*128+127].
    {
        float acc[3][4];
        #pragma unroll
        for (int c = 0; c < 3; ++c) {
            const float b = b1[c];
            #pragma unroll
            for (int j = 0; j < 4; ++j) acc[c][j] = b;
        }
        const unsigned a = tot_b + (unsigned)lane * 16u;
        float4 f;
        DS128(f, a, 0);    consume<0, 3, 4>(f, acc, w1, 20);
        DS128(f, a, 16);   consume<1, 3, 4>(f, acc, w1, 20);
        DS128(f, a, 32);   consume<2, 3, 4>(f, acc, w1, 20);
        DS128(f, a, 48);   consume<3, 3, 4>(f, acc, w1, 20);
        DS128(f, a, 64);   consume<4, 3, 4>(f, acc, w1, 20);
        DS128(f, a, 80);   consume<5, 3, 4>(f, acc, w1, 20);
        #pragma unroll
        for (int c = 0; c < 3; ++c) {
            float2 st;
            st.x = fmaxf(fmaxf(acc[c][0], acc[c][1]), 0.f);
            st.y = fmaxf(fmaxf(acc[c][2], acc[c][3]), 0.f);
            *reinterpret_cast<float2*>(&one1[c * 128 + 2 * lane]) = st;
        }
    }
    __syncthreads();

    // ---- Phase D: conv2 (3->6,K=20) + relu + maxpool2 -> [6][54], atomic add ----
    if (lane < 54) {
        float acc[6][2];
        #pragma unroll
        for (int c2 = 0; c2 < 6; ++c2) { acc[c2][0] = b2[c2]; acc[c2][1] = acc[c2][0]; }
        #pragma unroll
        for (int ch = 0; ch < 3; ++ch) {
            const unsigned a = one_b + (unsigned)ch * 512u + (unsigned)lane * 8u;
            const float* wch = w2 + ch * 20;     // index c2*60 + k
            float4 f;
            DS2X64(f, a, 0, 1);   consume<0, 6, 2>(f, acc, wch, 60);
            DS2X64(f, a, 2, 3);   consume<1, 6, 2>(f, acc, wch, 60);
            DS2X64(f, a, 4, 5);   consume<2, 6, 2>(f, acc, wch, 60);
            DS2X64(f, a, 6, 7);   consume<3, 6, 2>(f, acc, wch, 60);
            DS2X64(f, a, 8, 9);   consume<4, 6, 2>(f, acc, wch, 60);
            float f20;
            DS32(f20, a, 80);
            #pragma unroll
            for (int c2 = 0; c2 < 6; ++c2)
                acc[c2][1] = fmaf(f20, wch[c2 * 60 + 19], acc[c2][1]);
        }
        float* dst = sums + (size_t)cry * FDIM + lane;
        #pragma unroll
        for (int c2 = 0; c2 < 6; ++c2)
            atomicAdd(dst + c2 * 54, fmaxf(fmaxf(acc[c2][0], acc[c2][1]), 0.f));
    }
    if (lane == 0) atomicAdd(&counts[cry], 1.0f);
}

// -------- Kernel 2: per-crystal mean+relu, 324->32 softplus, 32->1 ----------
__global__ __launch_bounds__(64) void head_kernel(
    const float* __restrict__ sums, const float* __restrict__ counts,
    const float* __restrict__ lin_w, const float* __restrict__ lin_b,
    const float* __restrict__ lin1_w, const float* __restrict__ lin1_b,
    float* __restrict__ out)
{
    __shared__ float p[FDIM];
    const int c = blockIdx.x;
    const int lane = threadIdx.x;
    const float inv = 1.0f / fmaxf(counts[c], 1.0f);
    for (int i = lane; i < FDIM; i += 64)
        p[i] = fmaxf(sums[(size_t)c * FDIM + i] * inv, 0.f);
    __syncthreads();

    float r = 0.f;
    if (lane < 32) {
        float acc = lin_b[lane];
        const float* wrow = lin_w + lane * FDIM;
        #pragma unroll 4
        for (int i = 0; i < FDIM; ++i) acc = fmaf(p[i], wrow[i], acc);
        const float sp = (acc > 0.f) ? acc + log1pf(expf(-acc)) : log1pf(expf(acc));
        r = sp * lin1_w[lane];
    }
    #pragma unroll
    for (int off = 16; off; off >>= 1) r += __shfl_down(r, off);
    if (lane == 0) out[c] = r + lin1_b[0];
}

extern "C" void kernel_launch(void* const* d_in, const int* in_sizes, int n_in,
                              void* d_out, int out_size, void* d_ws, size_t ws_size,
                              hipStream_t stream) {
    (void)in_sizes; (void)n_in; (void)out_size; (void)ws_size;
    const float* oh    = (const float*)d_in[0];
    const float* env   = (const float*)d_in[1];
    const int*   idx   = (const int*)  d_in[2];
    // d_in[3] = num_segments (constant 4096)
    const float* wA    = (const float*)d_in[4];
    const float* bA    = (const float*)d_in[5];
    const float* w1    = (const float*)d_in[6];
    const float* b1    = (const float*)d_in[7];
    const float* w2    = (const float*)d_in[8];
    const float* b2    = (const float*)d_in[9];
    const float* lin_w = (const float*)d_in[10];
    const float* lin_b = (const float*)d_in[11];
    const float* lin1_w= (const float*)d_in[12];
    const float* lin1_b= (const float*)d_in[13];

    float* sums   = (float*)d_ws;             // [NC*FDIM]
    float* counts = sums + (size_t)NC * FDIM; // [NC]

    hipMemsetAsync(d_ws, 0, ((size_t)NC * FDIM + NC) * sizeof(float), stream);

    atom_kernel<<<M0 / 4, 256, 0, stream>>>(oh, env, idx, wA, bA, w1, b1, w2, b2,
                                            sums, counts);
    head_kernel<<<NC, 64, 0, stream>>>(sums, counts, lin_w, lin_b, lin1_w, lin1_b,
                                       (float*)d_out);
}

// Round 10
// 297.181 us; speedup vs baseline: 1.1210x; 1.1210x over previous
//
#include <hip/hip_runtime.h>
#include <math.h>

#define M0 131072
#define NC 4096
#define FDIM 324   // 6*54
#define APW 8      // atoms per wave (sorted idx -> mostly same crystal)

// ---- fine-grained LDS asm loads: value lands in VGPRs, consumed immediately ----
#define DS128(dst, addr, OFF)                                                  \
  asm volatile("ds_read_b128 %0, %1 offset:" #OFF "\n\t"                       \
               "s_waitcnt lgkmcnt(0)"                                          \
               : "=v"(dst) : "v"(addr))

#define DS2X64(dst, addr, O0, O1)                                              \
  asm volatile("ds_read2_b64 %0, %1 offset0:" #O0 " offset1:" #O1 "\n\t"       \
               "s_waitcnt lgkmcnt(0)"                                          \
               : "=v"(dst) : "v"(addr))

#define DS32(dst, addr, OFF)                                                   \
  asm volatile("ds_read_b32 %0, %1 offset:" #OFF "\n\t"                        \
               "s_waitcnt lgkmcnt(0)"                                          \
               : "=v"(dst) : "v"(addr))

// Wave-local phase fence: all prior LDS writes complete; compiler may not
// move memory ops across it. Replaces __syncthreads (buffers are per-wave).
#define FENCE() asm volatile("s_waitcnt lgkmcnt(0)" ::: "memory")

// Consume one 4-float chunk (window-relative floats 4M..4M+3) into
// acc[NOUT][NPOS]; weights stride wstride. All indices compile-time.
template<int M, int NOUT, int NPOS>
__device__ __forceinline__ void consume(const float4 f, float (&acc)[NOUT][NPOS],
                                        const float* __restrict__ w, const int wstride) {
    const float fi[4] = {f.x, f.y, f.z, f.w};
    #pragma unroll
    for (int i = 0; i < 4; ++i) {
        #pragma unroll
        for (int j = 0; j < NPOS; ++j) {
            const int k = 4 * M + i - j;
            if (k >= 0 && k < 20) {
                #pragma unroll
                for (int c = 0; c < NOUT; ++c)
                    acc[c][j] = fmaf(fi[i], w[c * wstride + k], acc[c][j]);
            }
        }
    }
}

// -------- Kernel 1: per-atom conv pipeline + register segment accumulation ----
// One wave handles APW consecutive atoms; flush to global atomics only on
// crystal-id change (sorted idx => ~1.25 flushes per wave).
__global__ __launch_bounds__(256, 4) void atom_kernel(
    const float* __restrict__ oh_g,    // [M0,92]
    const float* __restrict__ env_g,   // [M0,55]
    const int*   __restrict__ idx_g,   // [M0] sorted
    const float* __restrict__ wA, const float* __restrict__ bA,  // [3*20],[3]
    const float* __restrict__ w1, const float* __restrict__ b1,  // [3*20],[3]
    const float* __restrict__ w2, const float* __restrict__ b2,  // [6*3*20],[6]
    float* __restrict__ sums,          // [NC,324]
    float* __restrict__ counts)        // [NC]
{
    __shared__ __align__(16) float s_total[4][280];   // concat(atom[219], env[55]) = 274
    __shared__ __align__(16) float s_one1[4][384];    // conv1 pooled [3][128]; first 92 = one-hot scratch

    const int wave = threadIdx.x >> 6;
    const int lane = threadIdx.x & 63;

    float* total = s_total[wave];
    float* one1  = s_one1[wave];
    float* oh    = one1;                   // scratch alias: one-hot row [92]

    const unsigned tot_b = (unsigned)(size_t)total;
    const unsigned oh_b  = (unsigned)(size_t)oh;
    const unsigned one_b = (unsigned)(size_t)one1;

    const int wbase = (blockIdx.x * 4 + wave) * APW;

    float fa[6] = {0.f, 0.f, 0.f, 0.f, 0.f, 0.f};   // per-lane feature accum
    float cnt = 0.f;
    int cur = idx_g[wbase];

    for (int it = 0; it < APW; ++it) {
        const int atom = wbase + it;
        const int cry = idx_g[atom];                  // wave-uniform
        if (cry != cur) {                             // uniform branch: flush
            if (lane < 54) {
                float* dst = sums + (size_t)cur * FDIM + lane;
                #pragma unroll
                for (int c2 = 0; c2 < 6; ++c2) {
                    atomicAdd(dst + c2 * 54, fa[c2]);
                    fa[c2] = 0.f;
                }
            }
            if (lane == 0) atomicAdd(&counts[cur], cnt);
            cnt = 0.f;
            cur = cry;
        }

        // ---- Phase A: load one-hot (92) and env (55) ----
        if (lane < 46) {
            const float2 v = *reinterpret_cast<const float2*>(oh_g + (size_t)atom * 92 + 2 * lane);
            oh[2 * lane]     = v.x;
            oh[2 * lane + 1] = v.y;
        }
        if (lane < 55) {
            total[219 + lane] = env_g[(size_t)atom * 55 + lane];
        }
        FENCE();

        // ---- Phase B: conva -> relu -> total[0..218]  (37 lanes x 2 pos) ----
        if (lane < 37) {
            const int p2 = 2 * lane;
            float acc[3][2];
            #pragma unroll
            for (int c = 0; c < 3; ++c) { acc[c][0] = bA[c]; acc[c][1] = bA[c]; }
            const unsigned a = oh_b + (unsigned)lane * 8u;
            float4 f;
            DS2X64(f, a, 0, 1);   consume<0, 3, 2>(f, acc, wA, 20);
            DS2X64(f, a, 2, 3);   consume<1, 3, 2>(f, acc, wA, 20);
            DS2X64(f, a, 4, 5);   consume<2, 3, 2>(f, acc, wA, 20);
            DS2X64(f, a, 6, 7);   consume<3, 3, 2>(f, acc, wA, 20);
            DS2X64(f, a, 8, 9);   consume<4, 3, 2>(f, acc, wA, 20);
            float f20;
            DS32(f20, a, 80);     // window float 20: k=19 for position p2+1
            #pragma unroll
            for (int c = 0; c < 3; ++c) acc[c][1] = fmaf(f20, wA[c * 20 + 19], acc[c][1]);

            total[      p2] = fmaxf(acc[0][0], 0.f);
            total[ 73 + p2] = fmaxf(acc[1][0], 0.f);
            total[146 + p2] = fmaxf(acc[2][0], 0.f);
            if (p2 + 1 < 73) {
                total[      p2 + 1] = fmaxf(acc[0][1], 0.f);
                total[ 73 + p2 + 1] = fmaxf(acc[1][1], 0.f);
                total[146 + p2 + 1] = fmaxf(acc[2][1], 0.f);
            }
        }
        FENCE();

        // ---- Phase C: conv1 (1->3,K=20)+relu+maxpool2 -> one1[3][128] ----
        // lane q -> pooled {2q,2q+1} (unpooled 4q..4q+3); 6 x ds_read_b128.
        // q=63: pooled 127 is garbage -> dead slot one1[c*128+127].
        {
            float acc[3][4];
            #pragma unroll
            for (int c = 0; c < 3; ++c) {
                const float b = b1[c];
                #pragma unroll
                for (int j = 0; j < 4; ++j) acc[c][j] = b;
            }
            const unsigned a = tot_b + (unsigned)lane * 16u;
            float4 f;
            DS128(f, a, 0);    consume<0, 3, 4>(f, acc, w1, 20);
            DS128(f, a, 16);   consume<1, 3, 4>(f, acc, w1, 20);
            DS128(f, a, 32);   consume<2, 3, 4>(f, acc, w1, 20);
            DS128(f, a, 48);   consume<3, 3, 4>(f, acc, w1, 20);
            DS128(f, a, 64);   consume<4, 3, 4>(f, acc, w1, 20);
            DS128(f, a, 80);   consume<5, 3, 4>(f, acc, w1, 20);
            FENCE();           // phase-B asm reads of oh done; now safe to write one1
            #pragma unroll
            for (int c = 0; c < 3; ++c) {
                float2 st;
                st.x = fmaxf(fmaxf(acc[c][0], acc[c][1]), 0.f);
                st.y = fmaxf(fmaxf(acc[c][2], acc[c][3]), 0.f);
                *reinterpret_cast<float2*>(&one1[c * 128 + 2 * lane]) = st;
            }
        }
        FENCE();

        // ---- Phase D: conv2 (3->6,K=20)+relu+maxpool2 -> fa[6] accumulate ----
        if (lane < 54) {
            float acc[6][2];
            #pragma unroll
            for (int c2 = 0; c2 < 6; ++c2) { acc[c2][0] = b2[c2]; acc[c2][1] = acc[c2][0]; }
            #pragma unroll
            for (int ch = 0; ch < 3; ++ch) {
                const unsigned a = one_b + (unsigned)ch * 512u + (unsigned)lane * 8u;
                const float* wch = w2 + ch * 20;     // index c2*60 + k
                float4 f;
                DS2X64(f, a, 0, 1);   consume<0, 6, 2>(f, acc, wch, 60);
                DS2X64(f, a, 2, 3);   consume<1, 6, 2>(f, acc, wch, 60);
                DS2X64(f, a, 4, 5);   consume<2, 6, 2>(f, acc, wch, 60);
                DS2X64(f, a, 6, 7);   consume<3, 6, 2>(f, acc, wch, 60);
                DS2X64(f, a, 8, 9);   consume<4, 6, 2>(f, acc, wch, 60);
                float f20;
                DS32(f20, a, 80);
                #pragma unroll
                for (int c2 = 0; c2 < 6; ++c2)
                    acc[c2][1] = fmaf(f20, wch[c2 * 60 + 19], acc[c2][1]);
            }
            #pragma unroll
            for (int c2 = 0; c2 < 6; ++c2)
                fa[c2] += fmaxf(fmaxf(acc[c2][0], acc[c2][1]), 0.f);
        }
        cnt += 1.f;
        FENCE();   // phase-D reads of one1 done before next iter overwrites oh
    }

    // ---- final flush ----
    if (lane < 54) {
        float* dst = sums + (size_t)cur * FDIM + lane;
        #pragma unroll
        for (int c2 = 0; c2 < 6; ++c2) atomicAdd(dst + c2 * 54, fa[c2]);
    }
    if (lane == 0) atomicAdd(&counts[cur], cnt);
}

// -------- Kernel 2: per-crystal mean+relu, 324->32 softplus, 32->1 ----------
__global__ __launch_bounds__(64) void head_kernel(
    const float* __restrict__ sums, const float* __restrict__ counts,
    const float* __restrict__ lin_w, const float* __restrict__ lin_b,
    const float* __restrict__ lin1_w, const float* __restrict__ lin1_b,
    float* __restrict__ out)
{
    __shared__ float p[FDIM];
    const int c = blockIdx.x;
    const int lane = threadIdx.x;
    const float inv = 1.0f / fmaxf(counts[c], 1.0f);
    for (int i = lane; i < FDIM; i += 64)
        p[i] = fmaxf(sums[(size_t)c * FDIM + i] * inv, 0.f);
    __syncthreads();

    float r = 0.f;
    if (lane < 32) {
        float acc = lin_b[lane];
        const float* wrow = lin_w + lane * FDIM;
        #pragma unroll 4
        for (int i = 0; i < FDIM; ++i) acc = fmaf(p[i], wrow[i], acc);
        const float sp = (acc > 0.f) ? acc + log1pf(expf(-acc)) : log1pf(expf(acc));
        r = sp * lin1_w[lane];
    }
    #pragma unroll
    for (int off = 16; off; off >>= 1) r += __shfl_down(r, off);
    if (lane == 0) out[c] = r + lin1_b[0];
}

extern "C" void kernel_launch(void* const* d_in, const int* in_sizes, int n_in,
                              void* d_out, int out_size, void* d_ws, size_t ws_size,
                              hipStream_t stream) {
    (void)in_sizes; (void)n_in; (void)out_size; (void)ws_size;
    const float* oh    = (const float*)d_in[0];
    const float* env   = (const float*)d_in[1];
    const int*   idx   = (const int*)  d_in[2];
    // d_in[3] = num_segments (constant 4096)
    const float* wA    = (const float*)d_in[4];
    const float* bA    = (const float*)d_in[5];
    const float* w1    = (const float*)d_in[6];
    const float* b1    = (const float*)d_in[7];
    const float* w2    = (const float*)d_in[8];
    const float* b2    = (const float*)d_in[9];
    const float* lin_w = (const float*)d_in[10];
    const float* lin_b = (const float*)d_in[11];
    const float* lin1_w= (const float*)d_in[12];
    const float* lin1_b= (const float*)d_in[13];

    float* sums   = (float*)d_ws;             // [NC*FDIM]
    float* counts = sums + (size_t)NC * FDIM; // [NC]

    hipMemsetAsync(d_ws, 0, ((size_t)NC * FDIM + NC) * sizeof(float), stream);

    atom_kernel<<<M0 / (4 * APW), 256, 0, stream>>>(oh, env, idx, wA, bA, w1, b1,
                                                    w2, b2, sums, counts);
    head_kernel<<<NC, 64, 0, stream>>>(sums, counts, lin_w, lin_b, lin1_w, lin1_b,
                                       (float*)d_out);
}